// Round 2
// baseline (431.161 us; speedup 1.0000x reference)
//
#include <hip/hip_runtime.h>

// TwoLayerSAGE on MI355X (gfx950). Round 2.
// B=8, N=2048, IN_C=128, HID_C=256, OUT_C=32.
//
// R1 findings: k_agg1/k_agg2 were latency-bound (MfmaUtil 4.5%, VALU 11%,
// HBM 15%, occupancy = 1 block/CU) on a barrier-paced LDS-staging loop, and
// A (134 MB) was read twice. Restructure:
//   - k_prep_bits: A -> transposed bitmask bits[b][j][i/32] (4 MB), read A ONCE.
//   - agg GEMMs: no LDS staging, no barriers. A-fragments expanded from bits
//     via 16-entry LDS nibble LUT; B-fragments are direct 16B global loads
//     from pre-transposed bf16 operands (L1/L2-resident).
//   - layer-2 reorder: deginv*(maskT@h)@W2_l == deginv*(maskT@(h@W2_l)):
//     aggregate d=32 instead of d=256 (8x fewer agg2 FLOPs).
// ws (21.2 MB, aliased):
//   W1cT | W2cT | deg_inv | bits | [xT (4MB) -> h (8MB)] | [acat1 (8MB) -> hlT+hr]

#define B_   8
#define N_   2048
#define INC  128
#define HID  256
#define OUTC 32

typedef __attribute__((ext_vector_type(8))) __bf16 bf16x8;
typedef __attribute__((ext_vector_type(4))) float f32x4;
typedef __attribute__((ext_vector_type(4))) unsigned int u32x4;
typedef __attribute__((ext_vector_type(2))) unsigned int u32x2;

__device__ __forceinline__ unsigned short f2bf(float f) {
  unsigned int u = __float_as_uint(f);
  u += 0x7FFFu + ((u >> 16) & 1u);  // round-to-nearest-even
  return (unsigned short)(u >> 16);
}

__device__ __forceinline__ f32x4 mfma16(bf16x8 a, bf16x8 b, f32x4 c) {
  return __builtin_amdgcn_mfma_f32_16x16x32_bf16(a, b, c, 0, 0, 0);
}

__device__ __forceinline__ bf16x8 ones_frag() {
  union { unsigned short u[8]; bf16x8 v; } o;
#pragma unroll
  for (int i = 0; i < 8; i++) o.u[i] = 0x3F80;
  return o.v;
}

// ---------------------------------------------------------------------------
// A[b][i][j] -> bits[b][j][i/32] (bit i%32 = A!=0). Streaming read of A once.
// Block: 256 thr, tile [512 i][256 j]. Grid (32 = 8 jsplit x 4 isplit, 8 b).
__global__ __launch_bounds__(256) void k_prep_bits(
    const int* __restrict__ A, unsigned int* __restrict__ bits) {
  __shared__ unsigned int tl[256 * 17];
  const int b = blockIdx.y;
  const int js = blockIdx.x & 7, isp = blockIdx.x >> 3;
  const int j0 = js * 256, ib = isp * 512;
  const int t = threadIdx.x;
  const int* Ab = A + ((size_t)b * N_ + ib) * N_ + j0 + t;

  for (int q = 0; q < 16; q++) {  // word q covers i = ib + q*32 .. +32
    unsigned int wv = 0;
    const int* ap = Ab + (size_t)q * 32 * N_;
#pragma unroll
    for (int bit = 0; bit < 32; bit++)
      wv |= (ap[(size_t)bit * N_] != 0 ? 1u : 0u) << bit;
    tl[t * 17 + q] = wv;
  }
  __syncthreads();
  // coalesced writeback: global word (j_local, q) at j_local*64 + (ib>>5) + q
  unsigned int* bout = bits + ((size_t)b * N_ + j0) * 64 + (ib >> 5);
#pragma unroll
  for (int k = 0; k < 16; k++) {
    int g = k * 256 + t;
    int jl = g >> 4, q = g & 15;
    bout[(size_t)jl * 64 + q] = tl[jl * 17 + q];
  }
}

// ---------------------------------------------------------------------------
// Fused small prep:
//  part C (blocks 0..255):  x fp32 -> xT[b][d][i] bf16 AND acat1[b][i][128+d] bf16
//  part A (blocks 256..319): W1cT[e][k]: k<128 -> W1_l[k][e], else W1_r[k-128][e]
//  part B (blocks 320..335): W2cT[n][k]: n<32 -> W2_l[k][n], else W2_r[k][n-32]
__global__ __launch_bounds__(256) void k_prep_small(
    const float* __restrict__ x,
    const float* __restrict__ W1l, const float* __restrict__ W1r,
    const float* __restrict__ W2l, const float* __restrict__ W2r,
    unsigned short* __restrict__ xT, unsigned short* __restrict__ acat1,
    unsigned short* __restrict__ W1cT, unsigned short* __restrict__ W2cT) {
  const int bx = blockIdx.x, t = threadIdx.x;
  if (bx < 256) {
    __shared__ unsigned short xls[128 * 72];  // [d][i], pad 72 vs 64
    const int b = bx >> 5, it = bx & 31, i0 = it * 64;
    const int dq = (t & 31) * 4;   // d..d+3
    const int irow = t >> 5;       // + s*8 -> local i
#pragma unroll
    for (int s = 0; s < 8; s++) {
      int il = s * 8 + irow;
      int i = i0 + il;
      f32x4 v = *reinterpret_cast<const f32x4*>(x + ((size_t)(b * N_ + i)) * INC + dq);
      unsigned int p0 = f2bf(v[0]) | ((unsigned int)f2bf(v[1]) << 16);
      unsigned int p1 = f2bf(v[2]) | ((unsigned int)f2bf(v[3]) << 16);
      u32x2 pk = {p0, p1};
      *reinterpret_cast<u32x2*>(acat1 + ((size_t)(b * N_ + i)) * HID + 128 + dq) = pk;
      xls[(dq + 0) * 72 + il] = f2bf(v[0]);
      xls[(dq + 1) * 72 + il] = f2bf(v[1]);
      xls[(dq + 2) * 72 + il] = f2bf(v[2]);
      xls[(dq + 3) * 72 + il] = f2bf(v[3]);
    }
    __syncthreads();
    const int d = t >> 1, half = t & 1;
    const u32x4* src = reinterpret_cast<const u32x4*>(&xls[d * 72 + half * 32]);
    u32x4* dst = reinterpret_cast<u32x4*>(xT + ((size_t)(b * INC + d)) * N_ + i0 + half * 32);
#pragma unroll
    for (int q = 0; q < 4; q++) dst[q] = src[q];
  } else if (bx < 320) {
    int base = (bx - 256) * 1024 + t * 4;
#pragma unroll
    for (int q = 0; q < 4; q++) {
      int id = base + q;
      int e = id >> 8, k = id & 255;
      float v = (k < 128) ? W1l[k * 256 + e] : W1r[(k - 128) * 256 + e];
      W1cT[id] = f2bf(v);
    }
  } else {
    int base = (bx - 320) * 1024 + t * 4;
#pragma unroll
    for (int q = 0; q < 4; q++) {
      int id = base + q;
      int n = id >> 8, k = id & 255;
      float v = (n < 32) ? W2l[k * 32 + n] : W2r[k * 32 + (n - 32)];
      W2cT[id] = f2bf(v);
    }
  }
}

// ---------------------------------------------------------------------------
// Layer-1 aggregation, barrier-free: acat1[b][j][d<128] = deginv*(maskT@x),
// deg via ones-fragment MFMA. Wave: 16 j x 128 d. Block 4 waves (64 j).
// Grid (32, 8), 256 thr.
__global__ __launch_bounds__(256) void k_agg1(
    const unsigned int* __restrict__ bits, const unsigned short* __restrict__ xT,
    unsigned short* __restrict__ acat1, float* __restrict__ deg_inv) {
  __shared__ u32x2 lut[16];  // nibble -> 4 bf16 (0.0/1.0)
  const int t = threadIdx.x;
  if (t < 16) {
    unsigned int w0 = (t & 1 ? 0x3F80u : 0u) | (t & 2 ? 0x3F800000u : 0u);
    unsigned int w1 = (t & 4 ? 0x3F80u : 0u) | (t & 8 ? 0x3F800000u : 0u);
    u32x2 e = {w0, w1};
    lut[t] = e;
  }
  __syncthreads();
  const int w = t >> 6, l = t & 63, lr = l & 15, lq = l >> 4;
  const int b = blockIdx.y;
  const int j0w = blockIdx.x * 64 + w * 16;
  const unsigned int* bp = bits + ((size_t)(b * N_ + j0w + lr)) * 64;
  const unsigned short* xb = xT + (size_t)b * INC * N_;

  const f32x4 zero = {0.f, 0.f, 0.f, 0.f};
  f32x4 acc[8] = {zero, zero, zero, zero, zero, zero, zero, zero};
  f32x4 dacc = zero;
  const bf16x8 onesf = ones_frag();

  for (int k0 = 0; k0 < N_; k0 += 32) {
    unsigned int w32 = bp[k0 >> 5];
    unsigned int bval = (w32 >> (lq * 8)) & 0xFFu;
    union { u32x2 u2[2]; bf16x8 v; } af;
    af.u2[0] = lut[bval & 15u];
    af.u2[1] = lut[bval >> 4];
    dacc = mfma16(af.v, onesf, dacc);
#pragma unroll
    for (int ds = 0; ds < 8; ds++) {
      bf16x8 bfr = *reinterpret_cast<const bf16x8*>(
          xb + ((size_t)(ds * 16 + lr)) * N_ + k0 + lq * 8);
      acc[ds] = mfma16(af.v, bfr, acc[ds]);
    }
  }

  float dinv[4];
#pragma unroll
  for (int r = 0; r < 4; r++) dinv[r] = 1.0f / fmaxf(dacc[r], 1.0f);
  if (lr == 0) {
#pragma unroll
    for (int r = 0; r < 4; r++)
      deg_inv[b * N_ + j0w + lq * 4 + r] = dinv[r];
  }
  unsigned short* ag = acat1 + ((size_t)(b * N_ + j0w)) * HID;
#pragma unroll
  for (int ds = 0; ds < 8; ds++)
#pragma unroll
    for (int r = 0; r < 4; r++)
      ag[(size_t)(lq * 4 + r) * HID + ds * 16 + lr] = f2bf(acc[ds][r] * dinv[r]);
}

// ---------------------------------------------------------------------------
// Layer-1 dense, no LDS: h = relu(acat1 @ W1cT^T + b1). Wave: 16 j x 128 e.
// Grid (64 = 32 jt x 2 eh, 8), 256 thr.
__global__ __launch_bounds__(256) void k_dense1(
    const unsigned short* __restrict__ acat1, const unsigned short* __restrict__ W1cT,
    const float* __restrict__ b1, unsigned short* __restrict__ h) {
  const int t = threadIdx.x;
  const int w = t >> 6, l = t & 63, lr = l & 15, lq = l >> 4;
  const int b = blockIdx.y;
  const int jt = blockIdx.x >> 1, eh = blockIdx.x & 1;
  const int j0w = jt * 64 + w * 16, e0 = eh * 128;
  const unsigned short* ab = acat1 + ((size_t)(b * N_ + j0w + lr)) * HID;

  const f32x4 zero = {0.f, 0.f, 0.f, 0.f};
  f32x4 acc[8] = {zero, zero, zero, zero, zero, zero, zero, zero};
#pragma unroll
  for (int ks = 0; ks < 8; ks++) {
    bf16x8 af = *reinterpret_cast<const bf16x8*>(ab + ks * 32 + lq * 8);
#pragma unroll
    for (int es = 0; es < 8; es++) {
      bf16x8 bfr = *reinterpret_cast<const bf16x8*>(
          W1cT + ((size_t)(e0 + es * 16 + lr)) * HID + ks * 32 + lq * 8);
      acc[es] = mfma16(af, bfr, acc[es]);
    }
  }
  unsigned short* hB = h + ((size_t)(b * N_ + j0w)) * HID;
#pragma unroll
  for (int es = 0; es < 8; es++) {
    int e = e0 + es * 16 + lr;
    float bias = b1[e];
#pragma unroll
    for (int r = 0; r < 4; r++)
      hB[(size_t)(lq * 4 + r) * HID + e] = f2bf(fmaxf(acc[es][r] + bias, 0.0f));
  }
}

// ---------------------------------------------------------------------------
// hl/hr: hlT[b][c][i] = (h @ W2_l)^T bf16 (B-operand of agg2);
//        hr[b][i][c]  = h @ W2_r + b2 fp32. Wave: 16 i x 64 n. Grid (32, 8).
__global__ __launch_bounds__(256) void k_hl(
    const unsigned short* __restrict__ h, const unsigned short* __restrict__ W2cT,
    const float* __restrict__ b2, unsigned short* __restrict__ hlT,
    float* __restrict__ hr) {
  const int t = threadIdx.x;
  const int w = t >> 6, l = t & 63, lr = l & 15, lq = l >> 4;
  const int b = blockIdx.y;
  const int i0w = blockIdx.x * 64 + w * 16;
  const unsigned short* hb = h + ((size_t)(b * N_ + i0w + lr)) * HID;

  const f32x4 zero = {0.f, 0.f, 0.f, 0.f};
  f32x4 acc[4] = {zero, zero, zero, zero};
#pragma unroll
  for (int ks = 0; ks < 8; ks++) {
    bf16x8 af = *reinterpret_cast<const bf16x8*>(hb + ks * 32 + lq * 8);
#pragma unroll
    for (int ns = 0; ns < 4; ns++) {
      bf16x8 bfr = *reinterpret_cast<const bf16x8*>(
          W2cT + ((size_t)(ns * 16 + lr)) * HID + ks * 32 + lq * 8);
      acc[ns] = mfma16(af, bfr, acc[ns]);
    }
  }
#pragma unroll
  for (int ns = 0; ns < 2; ns++) {  // hl -> transposed bf16
    int c = ns * 16 + lr;
    unsigned int p0 = f2bf(acc[ns][0]) | ((unsigned int)f2bf(acc[ns][1]) << 16);
    unsigned int p1 = f2bf(acc[ns][2]) | ((unsigned int)f2bf(acc[ns][3]) << 16);
    u32x2 pk = {p0, p1};
    *reinterpret_cast<u32x2*>(hlT + ((size_t)(b * 32 + c)) * N_ + i0w + lq * 4) = pk;
  }
#pragma unroll
  for (int ns = 2; ns < 4; ns++) {  // hr fp32 + b2
    int c = (ns - 2) * 16 + lr;
    float bias = b2[c];
#pragma unroll
    for (int r = 0; r < 4; r++)
      hr[((size_t)(b * N_ + i0w + lq * 4 + r)) * OUTC + c] = acc[ns][r] + bias;
  }
}

// ---------------------------------------------------------------------------
// Fused layer-2 agg + epilogue + log_softmax, barrier-free K-loop:
// out = deginv*(maskT@hl) + hr; write log_softmax(out) and out.
// Wave: 16 j x 32 c. Grid (32, 8), 256 thr.
__global__ __launch_bounds__(256) void k_agg2out(
    const unsigned int* __restrict__ bits, const unsigned short* __restrict__ hlT,
    const float* __restrict__ deg_inv, const float* __restrict__ hr,
    float* __restrict__ out) {
  __shared__ u32x2 lut[16];
  const int t = threadIdx.x;
  if (t < 16) {
    unsigned int w0 = (t & 1 ? 0x3F80u : 0u) | (t & 2 ? 0x3F800000u : 0u);
    unsigned int w1 = (t & 4 ? 0x3F80u : 0u) | (t & 8 ? 0x3F800000u : 0u);
    u32x2 e = {w0, w1};
    lut[t] = e;
  }
  __syncthreads();
  const int w = t >> 6, l = t & 63, lr = l & 15, lq = l >> 4;
  const int b = blockIdx.y;
  const int j0w = blockIdx.x * 64 + w * 16;
  const unsigned int* bp = bits + ((size_t)(b * N_ + j0w + lr)) * 64;
  const unsigned short* hb = hlT + (size_t)b * 32 * N_;

  const f32x4 zero = {0.f, 0.f, 0.f, 0.f};
  f32x4 acc[2] = {zero, zero};

  for (int k0 = 0; k0 < N_; k0 += 32) {
    unsigned int w32 = bp[k0 >> 5];
    unsigned int bval = (w32 >> (lq * 8)) & 0xFFu;
    union { u32x2 u2[2]; bf16x8 v; } af;
    af.u2[0] = lut[bval & 15u];
    af.u2[1] = lut[bval >> 4];
#pragma unroll
    for (int cs = 0; cs < 2; cs++) {
      bf16x8 bfr = *reinterpret_cast<const bf16x8*>(
          hb + ((size_t)(cs * 16 + lr)) * N_ + k0 + lq * 8);
      acc[cs] = mfma16(af.v, bfr, acc[cs]);
    }
  }

  const size_t SZ = (size_t)B_ * N_ * OUTC;
#pragma unroll
  for (int r = 0; r < 4; r++) {
    int j = j0w + lq * 4 + r;
    float dv = deg_inv[b * N_ + j];
    size_t base = ((size_t)(b * N_ + j)) * OUTC;
    float v0 = acc[0][r] * dv + hr[base + lr];
    float v1 = acc[1][r] * dv + hr[base + 16 + lr];
    float m = fmaxf(v0, v1);
#pragma unroll
    for (int d = 1; d < 16; d <<= 1) m = fmaxf(m, __shfl_xor(m, d, 64));
    float s = __expf(v0 - m) + __expf(v1 - m);
#pragma unroll
    for (int d = 1; d < 16; d <<= 1) s += __shfl_xor(s, d, 64);
    float ls = m + __logf(s);
    out[base + lr] = v0 - ls;
    out[base + 16 + lr] = v1 - ls;
    out[SZ + base + lr] = v0;
    out[SZ + base + 16 + lr] = v1;
  }
}

// ---------------------------------------------------------------------------
extern "C" void kernel_launch(void* const* d_in, const int* in_sizes, int n_in,
                              void* d_out, int out_size, void* d_ws, size_t ws_size,
                              hipStream_t stream) {
  (void)in_sizes; (void)n_in; (void)out_size; (void)ws_size;
  const float* x   = (const float*)d_in[0];
  const int*   A   = (const int*)d_in[1];
  const float* W1l = (const float*)d_in[2];
  const float* W1r = (const float*)d_in[3];
  const float* b1  = (const float*)d_in[4];
  const float* W2l = (const float*)d_in[5];
  const float* W2r = (const float*)d_in[6];
  const float* b2  = (const float*)d_in[7];
  float* out = (float*)d_out;

  char* ws = (char*)d_ws;
  unsigned short* W1cT    = (unsigned short*)(ws + 0);         // 131072
  unsigned short* W2cT    = (unsigned short*)(ws + 131072);    // 32768
  float*          deg_inv = (float*)(ws + 163840);             // 65536
  unsigned int*   bits    = (unsigned int*)(ws + 229376);      // 4 MB -> 4423680
  // region R1 (8 MB): xT (4 MB, live prep->agg1) then h (8 MB, dense1->hl)
  unsigned short* xT      = (unsigned short*)(ws + 4423680);
  unsigned short* h       = (unsigned short*)(ws + 4423680);   // -> 12812288
  // region R2 (8 MB): acat1 (live prep->dense1) then hlT (1 MB) + hr (2 MB)
  unsigned short* acat1   = (unsigned short*)(ws + 12812288);  // -> 21200896
  unsigned short* hlT     = (unsigned short*)(ws + 12812288);
  float*          hr      = (float*)(ws + 13860864);

  k_prep_bits <<<dim3(32, 8), dim3(256), 0, stream>>>(A, bits);
  k_prep_small<<<dim3(336),   dim3(256), 0, stream>>>(x, W1l, W1r, W2l, W2r,
                                                      xT, acat1, W1cT, W2cT);
  k_agg1      <<<dim3(32, 8), dim3(256), 0, stream>>>(bits, xT, acat1, deg_inv);
  k_dense1    <<<dim3(64, 8), dim3(256), 0, stream>>>(acat1, W1cT, b1, h);
  k_hl        <<<dim3(32, 8), dim3(256), 0, stream>>>(h, W2cT, b2, hlT, hr);
  k_agg2out   <<<dim3(32, 8), dim3(256), 0, stream>>>(bits, hlT, deg_inv, hr, out);
}

// Round 3
// 321.672 us; speedup vs baseline: 1.3404x; 1.3404x over previous
//
#include <hip/hip_runtime.h>

// TwoLayerSAGE on MI355X (gfx950). Round 3.
// B=8, N=2048, IN_C=128, HID_C=256, OUT_C=32.
//
// R2 post-mortem: k_prep_bits latency-bound (HBM 5.9%, occ 10.7%) on strided
// per-thread bit packing; agg GEMMs expose only 1024 waves (4/CU).
// R3 restructure:
//   - k_bits: ballot-based compress+transpose. Wave reads 64x64 A-tile
//     row-coalesced, __ballot per row, per-lane bit extract -> transposed
//     u64 column word. 8192 waves, streaming at HBM/L3 rate.
//   - agg GEMMs: 4-way K-split per block (wave = 16j x full-width, 512 i's),
//     LDS partial combine -> grid 1024 blocks, 16 waves/CU.
//   - dense1+hl+hr fused: h lives only in LDS (16j x 256e tile).
// ws (17 MB): W1cT | W2cT | deg_inv | bits | [xT -> hlT+hr] | acat1

#define B_   8
#define N_   2048
#define INC  128
#define HID  256
#define OUTC 32

typedef __attribute__((ext_vector_type(8))) __bf16 bf16x8;
typedef __attribute__((ext_vector_type(4))) float f32x4;
typedef __attribute__((ext_vector_type(4))) unsigned int u32x4;
typedef __attribute__((ext_vector_type(2))) unsigned int u32x2;

__device__ __forceinline__ unsigned short f2bf(float f) {
  unsigned int u = __float_as_uint(f);
  u += 0x7FFFu + ((u >> 16) & 1u);  // round-to-nearest-even
  return (unsigned short)(u >> 16);
}

__device__ __forceinline__ f32x4 mfma16(bf16x8 a, bf16x8 b, f32x4 c) {
  return __builtin_amdgcn_mfma_f32_16x16x32_bf16(a, b, c, 0, 0, 0);
}

__device__ __forceinline__ bf16x8 ones_frag() {
  union { unsigned short u[8]; bf16x8 v; } o;
#pragma unroll
  for (int i = 0; i < 8; i++) o.u[i] = 0x3F80;
  return o.v;
}

__device__ __forceinline__ void lut_init(u32x2* lut, int t) {
  if (t < 16) {
    unsigned int w0 = (t & 1 ? 0x3F80u : 0u) | (t & 2 ? 0x3F800000u : 0u);
    unsigned int w1 = (t & 4 ? 0x3F80u : 0u) | (t & 8 ? 0x3F800000u : 0u);
    u32x2 e = {w0, w1};
    lut[t] = e;
  }
}

// ---------------------------------------------------------------------------
// A[b][i][j] -> bits[b][j][i/32] (bit i%32 = A!=0), fused transpose via ballot.
// One wave per 64x64 tile: row-coalesced loads, ballot -> per-lane column bit.
// Grid 2048 x 256 thr (8192 waves = 32 waves/CU).
__global__ __launch_bounds__(256, 8) void k_bits(
    const int* __restrict__ A, unsigned int* __restrict__ bits) {
  const int t = threadIdx.x;
  const int w = t >> 6, l = t & 63;
  const int gw = blockIdx.x * 4 + w;          // 0..8191
  const int b = gw >> 10;
  const int it = (gw >> 5) & 31, jt = gw & 31;
  const int i0 = it * 64, j0 = jt * 64;
  const int* Ap = A + ((size_t)(b * N_) + i0) * N_ + j0 + l;
  unsigned long long col = 0;
#pragma unroll 8
  for (int r = 0; r < 64; r++) {
    int a = Ap[(size_t)r * N_];
    unsigned long long m = __ballot(a != 0);
    col |= ((m >> l) & 1ull) << r;
  }
  *reinterpret_cast<unsigned long long*>(
      bits + ((size_t)(b * N_) + j0 + l) * 64 + (i0 >> 5)) = col;
}

// ---------------------------------------------------------------------------
// Fused small prep (unchanged from R2):
//  blocks 0..255:  x fp32 -> xT[b][d][i] bf16 AND acat1[b][i][128+d] bf16
//  blocks 256..319: W1cT[e][k]: k<128 -> W1_l[k][e], else W1_r[k-128][e]
//  blocks 320..335: W2cT[n][k]: n<32 -> W2_l[k][n], else W2_r[k][n-32]
__global__ __launch_bounds__(256) void k_prep_small(
    const float* __restrict__ x,
    const float* __restrict__ W1l, const float* __restrict__ W1r,
    const float* __restrict__ W2l, const float* __restrict__ W2r,
    unsigned short* __restrict__ xT, unsigned short* __restrict__ acat1,
    unsigned short* __restrict__ W1cT, unsigned short* __restrict__ W2cT) {
  const int bx = blockIdx.x, t = threadIdx.x;
  if (bx < 256) {
    __shared__ unsigned short xls[128 * 72];
    const int b = bx >> 5, it = bx & 31, i0 = it * 64;
    const int dq = (t & 31) * 4;
    const int irow = t >> 5;
#pragma unroll
    for (int s = 0; s < 8; s++) {
      int il = s * 8 + irow;
      int i = i0 + il;
      f32x4 v = *reinterpret_cast<const f32x4*>(x + ((size_t)(b * N_ + i)) * INC + dq);
      unsigned int p0 = f2bf(v[0]) | ((unsigned int)f2bf(v[1]) << 16);
      unsigned int p1 = f2bf(v[2]) | ((unsigned int)f2bf(v[3]) << 16);
      u32x2 pk = {p0, p1};
      *reinterpret_cast<u32x2*>(acat1 + ((size_t)(b * N_ + i)) * HID + 128 + dq) = pk;
      xls[(dq + 0) * 72 + il] = f2bf(v[0]);
      xls[(dq + 1) * 72 + il] = f2bf(v[1]);
      xls[(dq + 2) * 72 + il] = f2bf(v[2]);
      xls[(dq + 3) * 72 + il] = f2bf(v[3]);
    }
    __syncthreads();
    const int d = t >> 1, half = t & 1;
    const u32x4* src = reinterpret_cast<const u32x4*>(&xls[d * 72 + half * 32]);
    u32x4* dst = reinterpret_cast<u32x4*>(xT + ((size_t)(b * INC + d)) * N_ + i0 + half * 32);
#pragma unroll
    for (int q = 0; q < 4; q++) dst[q] = src[q];
  } else if (bx < 320) {
    int base = (bx - 256) * 1024 + t * 4;
#pragma unroll
    for (int q = 0; q < 4; q++) {
      int id = base + q;
      int e = id >> 8, k = id & 255;
      float v = (k < 128) ? W1l[k * 256 + e] : W1r[(k - 128) * 256 + e];
      W1cT[id] = f2bf(v);
    }
  } else {
    int base = (bx - 320) * 1024 + t * 4;
#pragma unroll
    for (int q = 0; q < 4; q++) {
      int id = base + q;
      int n = id >> 8, k = id & 255;
      float v = (n < 32) ? W2l[k * 32 + n] : W2r[k * 32 + (n - 32)];
      W2cT[id] = f2bf(v);
    }
  }
}

// ---------------------------------------------------------------------------
// Layer-1 aggregation, 4-way K-split: acat1[b][j][d<128] = deginv*(maskT@x).
// Block: 4 waves on ONE 16j x 128d tile, wave w covers i in [w*512, w*512+512).
// LDS combine of partials + deg (ones-MFMA). Grid (128, 8) = 16 waves/CU.
__global__ __launch_bounds__(256, 4) void k_agg1(
    const unsigned int* __restrict__ bits, const unsigned short* __restrict__ xT,
    unsigned short* __restrict__ acat1, float* __restrict__ deg_inv) {
  __shared__ u32x2 lut[16];
  __shared__ __align__(16) float part[4][8][64][4];  // [wave][ds][lane][r] 32KB
  __shared__ __align__(16) float pdeg[4][16][4];
  const int t = threadIdx.x;
  const int w = t >> 6, l = t & 63, lr = l & 15, lq = l >> 4;
  lut_init(lut, t);
  __syncthreads();
  const int b = blockIdx.y, j0 = blockIdx.x * 16;
  const unsigned int* bp = bits + ((size_t)(b * N_ + j0 + lr)) * 64 + w * 16;
  const unsigned short* xb = xT + (size_t)b * INC * N_ + w * 512;

  const f32x4 zero = {0.f, 0.f, 0.f, 0.f};
  f32x4 acc[8] = {zero, zero, zero, zero, zero, zero, zero, zero};
  f32x4 dacc = zero;
  const bf16x8 onesf = ones_frag();

  for (int s = 0; s < 16; s++) {
    unsigned int w32 = bp[s];
    unsigned int bval = (w32 >> (lq * 8)) & 0xFFu;
    union { u32x2 u2[2]; bf16x8 v; } af;
    af.u2[0] = lut[bval & 15u];
    af.u2[1] = lut[bval >> 4];
    dacc = mfma16(af.v, onesf, dacc);
#pragma unroll
    for (int ds = 0; ds < 8; ds++) {
      bf16x8 bfr = *reinterpret_cast<const bf16x8*>(
          xb + ((size_t)(ds * 16 + lr)) * N_ + s * 32 + lq * 8);
      acc[ds] = mfma16(af.v, bfr, acc[ds]);
    }
  }

#pragma unroll
  for (int ds = 0; ds < 8; ds++)
    *reinterpret_cast<f32x4*>(&part[w][ds][l][0]) = acc[ds];
  if (lr == 0) *reinterpret_cast<f32x4*>(&pdeg[w][lq][0]) = dacc;
  __syncthreads();

  float dinv[4];
#pragma unroll
  for (int r = 0; r < 4; r++) {
    float deg = pdeg[0][lq][r] + pdeg[1][lq][r] + pdeg[2][lq][r] + pdeg[3][lq][r];
    dinv[r] = 1.0f / fmaxf(deg, 1.0f);
  }
  if (w == 0 && lr == 0) {
#pragma unroll
    for (int r = 0; r < 4; r++)
      deg_inv[b * N_ + j0 + lq * 4 + r] = dinv[r];
  }
  unsigned short* ag = acat1 + ((size_t)(b * N_ + j0)) * HID;
#pragma unroll
  for (int dd = 0; dd < 2; dd++) {
    int ds = w * 2 + dd;
    f32x4 v0 = *reinterpret_cast<f32x4*>(&part[0][ds][l][0]);
    f32x4 v1 = *reinterpret_cast<f32x4*>(&part[1][ds][l][0]);
    f32x4 v2 = *reinterpret_cast<f32x4*>(&part[2][ds][l][0]);
    f32x4 v3 = *reinterpret_cast<f32x4*>(&part[3][ds][l][0]);
#pragma unroll
    for (int r = 0; r < 4; r++)
      ag[(size_t)(lq * 4 + r) * HID + ds * 16 + lr] =
          f2bf((v0[r] + v1[r] + v2[r] + v3[r]) * dinv[r]);
  }
}

// ---------------------------------------------------------------------------
// Fused dense1 + hl + hr: h = relu(acat1@W1cT^T + b1) (LDS only);
// hlT[b][c][i] = (h@W2_l)^T bf16; hr = h@W2_r + b2 fp32.
// Block: 4 waves on one 16j tile; phase1 wave w -> e-chunk w*64;
// phase2 wave w -> n-chunk w*16 (w<2: hl, else hr). Grid (128, 8).
__global__ __launch_bounds__(256, 4) void k_dense2(
    const unsigned short* __restrict__ acat1, const unsigned short* __restrict__ W1cT,
    const unsigned short* __restrict__ W2cT, const float* __restrict__ b1,
    const float* __restrict__ b2, unsigned short* __restrict__ hlT,
    float* __restrict__ hr) {
  __shared__ __align__(16) unsigned short hs[16 * 264];
  const int t = threadIdx.x;
  const int w = t >> 6, l = t & 63, lr = l & 15, lq = l >> 4;
  const int b = blockIdx.y, j0 = blockIdx.x * 16;
  const unsigned short* ab = acat1 + ((size_t)(b * N_ + j0 + lr)) * HID;
  const int e0 = w * 64;

  const f32x4 zero = {0.f, 0.f, 0.f, 0.f};
  f32x4 acc[4] = {zero, zero, zero, zero};
#pragma unroll
  for (int ks = 0; ks < 8; ks++) {
    bf16x8 af = *reinterpret_cast<const bf16x8*>(ab + ks * 32 + lq * 8);
#pragma unroll
    for (int es = 0; es < 4; es++) {
      bf16x8 bfr = *reinterpret_cast<const bf16x8*>(
          W1cT + ((size_t)(e0 + es * 16 + lr)) * HID + ks * 32 + lq * 8);
      acc[es] = mfma16(af, bfr, acc[es]);
    }
  }
#pragma unroll
  for (int es = 0; es < 4; es++) {
    int e = e0 + es * 16 + lr;
    float bias = b1[e];
#pragma unroll
    for (int r = 0; r < 4; r++)
      hs[(lq * 4 + r) * 264 + e] = f2bf(fmaxf(acc[es][r] + bias, 0.0f));
  }
  __syncthreads();

  f32x4 a2 = zero;
#pragma unroll
  for (int ks = 0; ks < 8; ks++) {
    bf16x8 af = *reinterpret_cast<const bf16x8*>(&hs[lr * 264 + ks * 32 + lq * 8]);
    bf16x8 bfr = *reinterpret_cast<const bf16x8*>(
        W2cT + ((size_t)(w * 16 + lr)) * HID + ks * 32 + lq * 8);
    a2 = mfma16(af, bfr, a2);
  }
  if (w < 2) {
    int c = w * 16 + lr;
    unsigned int p0 = f2bf(a2[0]) | ((unsigned int)f2bf(a2[1]) << 16);
    unsigned int p1 = f2bf(a2[2]) | ((unsigned int)f2bf(a2[3]) << 16);
    u32x2 pk = {p0, p1};
    *reinterpret_cast<u32x2*>(hlT + ((size_t)(b * 32 + c)) * N_ + j0 + lq * 4) = pk;
  } else {
    int c = (w - 2) * 16 + lr;
    float bias = b2[c];
#pragma unroll
    for (int r = 0; r < 4; r++)
      hr[((size_t)(b * N_ + j0 + lq * 4 + r)) * OUTC + c] = a2[r] + bias;
  }
}

// ---------------------------------------------------------------------------
// Fused layer-2 agg + epilogue + log_softmax, 4-way K-split.
// Block: 4 waves on one 16j x 32c tile, wave w covers i in [w*512, +512).
// Grid (128, 8).
__global__ __launch_bounds__(256, 4) void k_agg2out(
    const unsigned int* __restrict__ bits, const unsigned short* __restrict__ hlT,
    const float* __restrict__ deg_inv, const float* __restrict__ hr,
    float* __restrict__ out) {
  __shared__ u32x2 lut[16];
  __shared__ __align__(16) float part[4][64][2][4];  // 8KB
  const int t = threadIdx.x;
  const int w = t >> 6, l = t & 63, lr = l & 15, lq = l >> 4;
  lut_init(lut, t);
  __syncthreads();
  const int b = blockIdx.y, j0 = blockIdx.x * 16;
  const unsigned int* bp = bits + ((size_t)(b * N_ + j0 + lr)) * 64 + w * 16;
  const unsigned short* hb = hlT + (size_t)b * 32 * N_ + w * 512;

  const f32x4 zero = {0.f, 0.f, 0.f, 0.f};
  f32x4 acc[2] = {zero, zero};

  for (int s = 0; s < 16; s++) {
    unsigned int w32 = bp[s];
    unsigned int bval = (w32 >> (lq * 8)) & 0xFFu;
    union { u32x2 u2[2]; bf16x8 v; } af;
    af.u2[0] = lut[bval & 15u];
    af.u2[1] = lut[bval >> 4];
#pragma unroll
    for (int cs = 0; cs < 2; cs++) {
      bf16x8 bfr = *reinterpret_cast<const bf16x8*>(
          hb + ((size_t)(cs * 16 + lr)) * N_ + s * 32 + lq * 8);
      acc[cs] = mfma16(af.v, bfr, acc[cs]);
    }
  }

  *reinterpret_cast<f32x4*>(&part[w][l][0][0]) = acc[0];
  *reinterpret_cast<f32x4*>(&part[w][l][1][0]) = acc[1];
  __syncthreads();

  if (w == 0) {
    const size_t SZ = (size_t)B_ * N_ * OUTC;
#pragma unroll
    for (int r = 0; r < 4; r++) {
      int j = j0 + lq * 4 + r;
      float dv = deg_inv[b * N_ + j];
      size_t base = ((size_t)(b * N_ + j)) * OUTC;
      float v0 = (part[0][l][0][r] + part[1][l][0][r] +
                  part[2][l][0][r] + part[3][l][0][r]) * dv + hr[base + lr];
      float v1 = (part[0][l][1][r] + part[1][l][1][r] +
                  part[2][l][1][r] + part[3][l][1][r]) * dv + hr[base + 16 + lr];
      float m = fmaxf(v0, v1);
#pragma unroll
      for (int d = 1; d < 16; d <<= 1) m = fmaxf(m, __shfl_xor(m, d, 64));
      float s = __expf(v0 - m) + __expf(v1 - m);
#pragma unroll
      for (int d = 1; d < 16; d <<= 1) s += __shfl_xor(s, d, 64);
      float ls = m + __logf(s);
      out[base + lr] = v0 - ls;
      out[base + 16 + lr] = v1 - ls;
      out[SZ + base + lr] = v0;
      out[SZ + base + 16 + lr] = v1;
    }
  }
}

// ---------------------------------------------------------------------------
extern "C" void kernel_launch(void* const* d_in, const int* in_sizes, int n_in,
                              void* d_out, int out_size, void* d_ws, size_t ws_size,
                              hipStream_t stream) {
  (void)in_sizes; (void)n_in; (void)out_size; (void)ws_size;
  const float* x   = (const float*)d_in[0];
  const int*   A   = (const int*)d_in[1];
  const float* W1l = (const float*)d_in[2];
  const float* W1r = (const float*)d_in[3];
  const float* b1  = (const float*)d_in[4];
  const float* W2l = (const float*)d_in[5];
  const float* W2r = (const float*)d_in[6];
  const float* b2  = (const float*)d_in[7];
  float* out = (float*)d_out;

  char* ws = (char*)d_ws;
  unsigned short* W1cT    = (unsigned short*)(ws + 0);        // 131072
  unsigned short* W2cT    = (unsigned short*)(ws + 131072);   // 32768 -> 163840
  float*          deg_inv = (float*)(ws + 163840);            // 65536 -> 229376
  unsigned int*   bits    = (unsigned int*)(ws + 229376);     // 4 MB -> 4423680
  // region R1 (4 MB): xT (live prep->agg1), then hlT (1MB) + hr (2MB)
  unsigned short* xT      = (unsigned short*)(ws + 4423680);  // -> 8617984
  unsigned short* hlT     = (unsigned short*)(ws + 4423680);  // 1 MB -> 5472256
  float*          hr      = (float*)(ws + 5472256);           // 2 MB -> 7569408
  unsigned short* acat1   = (unsigned short*)(ws + 8617984);  // 8 MB -> 17006592

  k_bits      <<<dim3(2048),   dim3(256), 0, stream>>>(A, bits);
  k_prep_small<<<dim3(336),    dim3(256), 0, stream>>>(x, W1l, W1r, W2l, W2r,
                                                       xT, acat1, W1cT, W2cT);
  k_agg1      <<<dim3(128, 8), dim3(256), 0, stream>>>(bits, xT, acat1, deg_inv);
  k_dense2    <<<dim3(128, 8), dim3(256), 0, stream>>>(acat1, W1cT, W2cT, b1, b2,
                                                       hlT, hr);
  k_agg2out   <<<dim3(128, 8), dim3(256), 0, stream>>>(bits, hlT, deg_inv, hr, out);
}

// Round 4
// 287.808 us; speedup vs baseline: 1.4981x; 1.1177x over previous
//
#include <hip/hip_runtime.h>

// TwoLayerSAGE on MI355X (gfx950). Round 4.
// B=8, N=2048, IN_C=128, HID_C=256, OUT_C=32.
//
// R3 post-mortem: all kernels now < 77 us (harness 537 MB ws-poison fills at
// ~78 us own the top-5). R4: halve L2 re-read traffic by widening wave tiles
// to 32 j (B-fragments reused across 2 A-frag sets), 4 dispatches instead of 5.
//   k_prep:   A -> transposed bitmask via ballot (read A once) + x->xT/acat1 +
//             weight packs, one kernel.
//   k_agg1:   maskT@x, 32j x 128d per wave, 4-way K-split, asymmetric LDS
//             combine (waves 1-3 dump 48 KB partials, wave 0 combines).
//   k_dense2: h=relu([agg1|x]@W1+b1) in LDS; hlT=(h@W2_l)^T; hr=h@W2_r+b2.
//   k_agg2out: deginv*(maskT@hl)+hr, fused log_softmax (layer-2 reorder:
//             aggregate d=32 not 256).
// ws (17 MB): W1cT | W2cT | deg_inv | bits | [xT -> hlT+hr] | acat1

#define B_   8
#define N_   2048
#define INC  128
#define HID  256
#define OUTC 32

typedef __attribute__((ext_vector_type(8))) __bf16 bf16x8;
typedef __attribute__((ext_vector_type(4))) float f32x4;
typedef __attribute__((ext_vector_type(4))) unsigned int u32x4;
typedef __attribute__((ext_vector_type(2))) unsigned int u32x2;

__device__ __forceinline__ unsigned short f2bf(float f) {
  unsigned int u = __float_as_uint(f);
  u += 0x7FFFu + ((u >> 16) & 1u);  // round-to-nearest-even
  return (unsigned short)(u >> 16);
}

__device__ __forceinline__ f32x4 mfma16(bf16x8 a, bf16x8 b, f32x4 c) {
  return __builtin_amdgcn_mfma_f32_16x16x32_bf16(a, b, c, 0, 0, 0);
}

__device__ __forceinline__ bf16x8 ones_frag() {
  union { unsigned short u[8]; bf16x8 v; } o;
#pragma unroll
  for (int i = 0; i < 8; i++) o.u[i] = 0x3F80;
  return o.v;
}

__device__ __forceinline__ void lut_init(u32x2* lut, int t) {
  if (t < 16) {
    unsigned int w0 = (t & 1 ? 0x3F80u : 0u) | (t & 2 ? 0x3F800000u : 0u);
    unsigned int w1 = (t & 4 ? 0x3F80u : 0u) | (t & 8 ? 0x3F800000u : 0u);
    u32x2 e = {w0, w1};
    lut[t] = e;
  }
}

// nibble-LUT expansion: 8 mask bits -> bf16x8 (0.0/1.0)
__device__ __forceinline__ bf16x8 expand8(const u32x2* lut, unsigned int bval) {
  union { u32x2 u2[2]; bf16x8 v; } af;
  af.u2[0] = lut[bval & 15u];
  af.u2[1] = lut[bval >> 4];
  return af.v;
}

// ---------------------------------------------------------------------------
// Fused prep. Blocks:
//  [0,2048):    A[b][i][j] -> bits[b][j][i/32] via per-wave 64x64 ballot tiles
//  [2048,2304): x fp32 -> xT[b][d][i] bf16 AND acat1[b][i][128+d] bf16
//  [2304,2368): W1cT[e][k]: k<128 -> W1_l[k][e], else W1_r[k-128][e]
//  [2368,2384): W2cT[n][k]: n<32 -> W2_l[k][n], else W2_r[k][n-32]
__global__ __launch_bounds__(256, 8) void k_prep(
    const int* __restrict__ A, const float* __restrict__ x,
    const float* __restrict__ W1l, const float* __restrict__ W1r,
    const float* __restrict__ W2l, const float* __restrict__ W2r,
    unsigned int* __restrict__ bits, unsigned short* __restrict__ xT,
    unsigned short* __restrict__ acat1,
    unsigned short* __restrict__ W1cT, unsigned short* __restrict__ W2cT) {
  __shared__ unsigned short xls[128 * 72];
  const int bx = blockIdx.x, t = threadIdx.x;
  if (bx < 2048) {
    const int w = t >> 6, l = t & 63;
    const int gw = bx * 4 + w;  // 0..8191
    const int b = gw >> 10;
    const int it = (gw >> 5) & 31, jt = gw & 31;
    const int i0 = it * 64, j0 = jt * 64;
    const int* Ap = A + ((size_t)(b * N_) + i0) * N_ + j0 + l;
    unsigned long long col = 0;
#pragma unroll 8
    for (int r = 0; r < 64; r++) {
      int a = Ap[(size_t)r * N_];
      unsigned long long m = __ballot(a != 0);
      col |= ((m >> l) & 1ull) << r;
    }
    *reinterpret_cast<unsigned long long*>(
        bits + ((size_t)(b * N_) + j0 + l) * 64 + (i0 >> 5)) = col;
  } else if (bx < 2304) {
    const int bb = bx - 2048;
    const int b = bb >> 5, it = bb & 31, i0 = it * 64;
    const int dq = (t & 31) * 4;
    const int irow = t >> 5;
#pragma unroll
    for (int s = 0; s < 8; s++) {
      int il = s * 8 + irow;
      int i = i0 + il;
      f32x4 v = *reinterpret_cast<const f32x4*>(x + ((size_t)(b * N_ + i)) * INC + dq);
      unsigned int p0 = f2bf(v[0]) | ((unsigned int)f2bf(v[1]) << 16);
      unsigned int p1 = f2bf(v[2]) | ((unsigned int)f2bf(v[3]) << 16);
      u32x2 pk = {p0, p1};
      *reinterpret_cast<u32x2*>(acat1 + ((size_t)(b * N_ + i)) * HID + 128 + dq) = pk;
      xls[(dq + 0) * 72 + il] = f2bf(v[0]);
      xls[(dq + 1) * 72 + il] = f2bf(v[1]);
      xls[(dq + 2) * 72 + il] = f2bf(v[2]);
      xls[(dq + 3) * 72 + il] = f2bf(v[3]);
    }
    __syncthreads();
    const int d = t >> 1, half = t & 1;
    const u32x4* src = reinterpret_cast<const u32x4*>(&xls[d * 72 + half * 32]);
    u32x4* dst = reinterpret_cast<u32x4*>(xT + ((size_t)(b * INC + d)) * N_ + i0 + half * 32);
#pragma unroll
    for (int q = 0; q < 4; q++) dst[q] = src[q];
  } else if (bx < 2368) {
    int base = (bx - 2304) * 1024 + t * 4;
#pragma unroll
    for (int q = 0; q < 4; q++) {
      int id = base + q;
      int e = id >> 8, k = id & 255;
      float v = (k < 128) ? W1l[k * 256 + e] : W1r[(k - 128) * 256 + e];
      W1cT[id] = f2bf(v);
    }
  } else {
    int base = (bx - 2368) * 1024 + t * 4;
#pragma unroll
    for (int q = 0; q < 4; q++) {
      int id = base + q;
      int n = id >> 8, k = id & 255;
      float v = (n < 32) ? W2l[k * 32 + n] : W2r[k * 32 + (n - 32)];
      W2cT[id] = f2bf(v);
    }
  }
}

// ---------------------------------------------------------------------------
// Layer-1 aggregation: acat1[b][j][d<128] = deginv*(maskT@x), deg in-GEMM.
// Wave tile: 32 j x 128 d (2 A-frag sets share each B-load). 4-way K-split
// (wave w -> i in [w*512,+512)). Waves 1-3 dump 48 KB fp32 partials to LDS;
// wave 0 combines in-register, scales, stores. Grid (64, 8), 256 thr.
__global__ __launch_bounds__(256, 2) void k_agg1(
    const unsigned int* __restrict__ bits, const unsigned short* __restrict__ xT,
    unsigned short* __restrict__ acat1, float* __restrict__ deg_inv) {
  __shared__ u32x2 lut[16];
  __shared__ __align__(16) float part[3][2][8][64][4];  // 48 KB
  __shared__ __align__(16) float pdeg[3][2][16][4];     // 1.5 KB
  const int t = threadIdx.x;
  const int w = t >> 6, l = t & 63, lr = l & 15, lq = l >> 4;
  lut_init(lut, t);
  __syncthreads();
  const int b = blockIdx.y, j0 = blockIdx.x * 32;
  const unsigned int* bp0 = bits + ((size_t)(b * N_ + j0 + lr)) * 64 + w * 16;
  const unsigned int* bp1 = bp0 + (size_t)16 * 64;  // jt=1 -> j += 16
  const unsigned short* xb = xT + (size_t)b * INC * N_ + w * 512;

  const f32x4 zero = {0.f, 0.f, 0.f, 0.f};
  f32x4 acc[2][8];
#pragma unroll
  for (int jt = 0; jt < 2; jt++)
#pragma unroll
    for (int ds = 0; ds < 8; ds++) acc[jt][ds] = zero;
  f32x4 dacc[2] = {zero, zero};
  const bf16x8 onesf = ones_frag();

  for (int s = 0; s < 16; s++) {
    bf16x8 af0 = expand8(lut, (bp0[s] >> (lq * 8)) & 0xFFu);
    bf16x8 af1 = expand8(lut, (bp1[s] >> (lq * 8)) & 0xFFu);
    dacc[0] = mfma16(af0, onesf, dacc[0]);
    dacc[1] = mfma16(af1, onesf, dacc[1]);
#pragma unroll
    for (int ds = 0; ds < 8; ds++) {
      bf16x8 bfr = *reinterpret_cast<const bf16x8*>(
          xb + ((size_t)(ds * 16 + lr)) * N_ + s * 32 + lq * 8);
      acc[0][ds] = mfma16(af0, bfr, acc[0][ds]);
      acc[1][ds] = mfma16(af1, bfr, acc[1][ds]);
    }
  }

  if (w > 0) {
#pragma unroll
    for (int jt = 0; jt < 2; jt++) {
#pragma unroll
      for (int ds = 0; ds < 8; ds++)
        *reinterpret_cast<f32x4*>(&part[w - 1][jt][ds][l][0]) = acc[jt][ds];
      if (lr == 0) *reinterpret_cast<f32x4*>(&pdeg[w - 1][jt][lq][0]) = dacc[jt];
    }
  }
  __syncthreads();
  if (w != 0) return;

  unsigned short* ag = acat1 + ((size_t)(b * N_ + j0)) * HID;
#pragma unroll
  for (int jt = 0; jt < 2; jt++) {
    float dinv[4];
#pragma unroll
    for (int r = 0; r < 4; r++) {
      float deg = dacc[jt][r] + pdeg[0][jt][lq][r] + pdeg[1][jt][lq][r] +
                  pdeg[2][jt][lq][r];
      dinv[r] = 1.0f / fmaxf(deg, 1.0f);
    }
    if (lr == 0) {
#pragma unroll
      for (int r = 0; r < 4; r++)
        deg_inv[b * N_ + j0 + jt * 16 + lq * 4 + r] = dinv[r];
    }
#pragma unroll
    for (int ds = 0; ds < 8; ds++) {
      f32x4 v0 = *reinterpret_cast<f32x4*>(&part[0][jt][ds][l][0]);
      f32x4 v1 = *reinterpret_cast<f32x4*>(&part[1][jt][ds][l][0]);
      f32x4 v2 = *reinterpret_cast<f32x4*>(&part[2][jt][ds][l][0]);
#pragma unroll
      for (int r = 0; r < 4; r++)
        ag[(size_t)(jt * 16 + lq * 4 + r) * HID + ds * 16 + lr] =
            f2bf((acc[jt][ds][r] + v0[r] + v1[r] + v2[r]) * dinv[r]);
    }
  }
}

// ---------------------------------------------------------------------------
// Fused dense1 + hl + hr over a 32-j tile:
//  phase1: h = relu(acat1@W1cT^T + b1) -> LDS hs[32][264] (wave w: e-chunk w*64)
//  phase2: wave w: jt = w&1; w<2 -> hlT[b][c][i]=(h@W2_l)^T bf16 (n 0..31);
//          w>=2 -> hr = h@W2_r + b2 fp32 (n 32..63). Grid (64, 8), 256 thr.
__global__ __launch_bounds__(256, 2) void k_dense2(
    const unsigned short* __restrict__ acat1, const unsigned short* __restrict__ W1cT,
    const unsigned short* __restrict__ W2cT, const float* __restrict__ b1,
    const float* __restrict__ b2, unsigned short* __restrict__ hlT,
    float* __restrict__ hr) {
  __shared__ __align__(16) unsigned short hs[32 * 264];
  const int t = threadIdx.x;
  const int w = t >> 6, l = t & 63, lr = l & 15, lq = l >> 4;
  const int b = blockIdx.y, j0 = blockIdx.x * 32;
  const int e0 = w * 64;

  const f32x4 zero = {0.f, 0.f, 0.f, 0.f};
  f32x4 acc[2][4];
#pragma unroll
  for (int jt = 0; jt < 2; jt++)
#pragma unroll
    for (int es = 0; es < 4; es++) acc[jt][es] = zero;

#pragma unroll
  for (int ks = 0; ks < 8; ks++) {
    bf16x8 af0 = *reinterpret_cast<const bf16x8*>(
        acat1 + ((size_t)(b * N_ + j0 + lr)) * HID + ks * 32 + lq * 8);
    bf16x8 af1 = *reinterpret_cast<const bf16x8*>(
        acat1 + ((size_t)(b * N_ + j0 + 16 + lr)) * HID + ks * 32 + lq * 8);
#pragma unroll
    for (int es = 0; es < 4; es++) {
      bf16x8 bfr = *reinterpret_cast<const bf16x8*>(
          W1cT + ((size_t)(e0 + es * 16 + lr)) * HID + ks * 32 + lq * 8);
      acc[0][es] = mfma16(af0, bfr, acc[0][es]);
      acc[1][es] = mfma16(af1, bfr, acc[1][es]);
    }
  }
#pragma unroll
  for (int jt = 0; jt < 2; jt++)
#pragma unroll
    for (int es = 0; es < 4; es++) {
      int e = e0 + es * 16 + lr;
      float bias = b1[e];
#pragma unroll
      for (int r = 0; r < 4; r++)
        hs[(jt * 16 + lq * 4 + r) * 264 + e] = f2bf(fmaxf(acc[jt][es][r] + bias, 0.0f));
    }
  __syncthreads();

  const int jt = w & 1, nh = w >> 1;
  f32x4 a2[2] = {zero, zero};
#pragma unroll
  for (int ks = 0; ks < 8; ks++) {
    bf16x8 af = *reinterpret_cast<const bf16x8*>(&hs[(jt * 16 + lr) * 264 + ks * 32 + lq * 8]);
#pragma unroll
    for (int ns = 0; ns < 2; ns++) {
      bf16x8 bfr = *reinterpret_cast<const bf16x8*>(
          W2cT + ((size_t)(nh * 32 + ns * 16 + lr)) * HID + ks * 32 + lq * 8);
      a2[ns] = mfma16(af, bfr, a2[ns]);
    }
  }
  if (nh == 0) {
#pragma unroll
    for (int ns = 0; ns < 2; ns++) {
      int c = ns * 16 + lr;
      unsigned int p0 = f2bf(a2[ns][0]) | ((unsigned int)f2bf(a2[ns][1]) << 16);
      unsigned int p1 = f2bf(a2[ns][2]) | ((unsigned int)f2bf(a2[ns][3]) << 16);
      u32x2 pk = {p0, p1};
      *reinterpret_cast<u32x2*>(
          hlT + ((size_t)(b * 32 + c)) * N_ + j0 + jt * 16 + lq * 4) = pk;
    }
  } else {
#pragma unroll
    for (int ns = 0; ns < 2; ns++) {
      int c = ns * 16 + lr;
      float bias = b2[c];
#pragma unroll
      for (int r = 0; r < 4; r++)
        hr[((size_t)(b * N_ + j0 + jt * 16 + lq * 4 + r)) * OUTC + c] = a2[ns][r] + bias;
    }
  }
}

// ---------------------------------------------------------------------------
// Fused layer-2 agg + epilogue + log_softmax. Wave tile 32 j x 32 c, 4-way
// K-split, symmetric 16 KB LDS combine; waves 0,1 do the epilogue (jt = w).
// Grid (64, 8), 256 thr.
__global__ __launch_bounds__(256, 2) void k_agg2out(
    const unsigned int* __restrict__ bits, const unsigned short* __restrict__ hlT,
    const float* __restrict__ deg_inv, const float* __restrict__ hr,
    float* __restrict__ out) {
  __shared__ u32x2 lut[16];
  __shared__ __align__(16) float part[4][2][2][64][4];  // 16 KB
  const int t = threadIdx.x;
  const int w = t >> 6, l = t & 63, lr = l & 15, lq = l >> 4;
  lut_init(lut, t);
  __syncthreads();
  const int b = blockIdx.y, j0 = blockIdx.x * 32;
  const unsigned int* bp0 = bits + ((size_t)(b * N_ + j0 + lr)) * 64 + w * 16;
  const unsigned int* bp1 = bp0 + (size_t)16 * 64;
  const unsigned short* hb = hlT + (size_t)b * 32 * N_ + w * 512;

  const f32x4 zero = {0.f, 0.f, 0.f, 0.f};
  f32x4 acc[2][2] = {{zero, zero}, {zero, zero}};

  for (int s = 0; s < 16; s++) {
    bf16x8 af0 = expand8(lut, (bp0[s] >> (lq * 8)) & 0xFFu);
    bf16x8 af1 = expand8(lut, (bp1[s] >> (lq * 8)) & 0xFFu);
#pragma unroll
    for (int cs = 0; cs < 2; cs++) {
      bf16x8 bfr = *reinterpret_cast<const bf16x8*>(
          hb + ((size_t)(cs * 16 + lr)) * N_ + s * 32 + lq * 8);
      acc[0][cs] = mfma16(af0, bfr, acc[0][cs]);
      acc[1][cs] = mfma16(af1, bfr, acc[1][cs]);
    }
  }
#pragma unroll
  for (int jt = 0; jt < 2; jt++)
#pragma unroll
    for (int cs = 0; cs < 2; cs++)
      *reinterpret_cast<f32x4*>(&part[w][jt][cs][l][0]) = acc[jt][cs];
  __syncthreads();
  if (w >= 2) return;

  const int jt = w;
  const size_t SZ = (size_t)B_ * N_ * OUTC;
#pragma unroll
  for (int r = 0; r < 4; r++) {
    int j = j0 + jt * 16 + lq * 4 + r;
    float dv = deg_inv[b * N_ + j];
    size_t base = ((size_t)(b * N_ + j)) * OUTC;
    float v0 = (part[0][jt][0][l][r] + part[1][jt][0][l][r] +
                part[2][jt][0][l][r] + part[3][jt][0][l][r]) * dv + hr[base + lr];
    float v1 = (part[0][jt][1][l][r] + part[1][jt][1][l][r] +
                part[2][jt][1][l][r] + part[3][jt][1][l][r]) * dv + hr[base + 16 + lr];
    float m = fmaxf(v0, v1);
#pragma unroll
    for (int d = 1; d < 16; d <<= 1) m = fmaxf(m, __shfl_xor(m, d, 64));
    float s = __expf(v0 - m) + __expf(v1 - m);
#pragma unroll
    for (int d = 1; d < 16; d <<= 1) s += __shfl_xor(s, d, 64);
    float ls = m + __logf(s);
    out[base + lr] = v0 - ls;
    out[base + 16 + lr] = v1 - ls;
    out[SZ + base + lr] = v0;
    out[SZ + base + 16 + lr] = v1;
  }
}

// ---------------------------------------------------------------------------
extern "C" void kernel_launch(void* const* d_in, const int* in_sizes, int n_in,
                              void* d_out, int out_size, void* d_ws, size_t ws_size,
                              hipStream_t stream) {
  (void)in_sizes; (void)n_in; (void)out_size; (void)ws_size;
  const float* x   = (const float*)d_in[0];
  const int*   A   = (const int*)d_in[1];
  const float* W1l = (const float*)d_in[2];
  const float* W1r = (const float*)d_in[3];
  const float* b1  = (const float*)d_in[4];
  const float* W2l = (const float*)d_in[5];
  const float* W2r = (const float*)d_in[6];
  const float* b2  = (const float*)d_in[7];
  float* out = (float*)d_out;

  char* ws = (char*)d_ws;
  unsigned short* W1cT    = (unsigned short*)(ws + 0);        // 131072
  unsigned short* W2cT    = (unsigned short*)(ws + 131072);   // 32768 -> 163840
  float*          deg_inv = (float*)(ws + 163840);            // 65536 -> 229376
  unsigned int*   bits    = (unsigned int*)(ws + 229376);     // 4 MB -> 4423680
  // region R1 (4 MB): xT (live prep->agg1), then hlT (1MB) + hr (2MB)
  unsigned short* xT      = (unsigned short*)(ws + 4423680);  // -> 8617984
  unsigned short* hlT     = (unsigned short*)(ws + 4423680);  // 1 MB -> 5472256
  float*          hr      = (float*)(ws + 5472256);           // 2 MB -> 7569408
  unsigned short* acat1   = (unsigned short*)(ws + 8617984);  // 8 MB -> 17006592

  k_prep   <<<dim3(2384),  dim3(256), 0, stream>>>(A, x, W1l, W1r, W2l, W2r,
                                                   bits, xT, acat1, W1cT, W2cT);
  k_agg1   <<<dim3(64, 8), dim3(256), 0, stream>>>(bits, xT, acat1, deg_inv);
  k_dense2 <<<dim3(64, 8), dim3(256), 0, stream>>>(acat1, W1cT, W2cT, b1, b2,
                                                   hlT, hr);
  k_agg2out<<<dim3(64, 8), dim3(256), 0, stream>>>(bits, hlT, deg_inv, hr, out);
}

// Round 5
// 284.342 us; speedup vs baseline: 1.5163x; 1.0122x over previous
//
#include <hip/hip_runtime.h>

// TwoLayerSAGE on MI355X (gfx950). Round 5.
// B=8, N=2048, IN_C=128, HID_C=256, OUT_C=32.
//
// R4 post-mortem: traffic-halving saved 34 us => agg B-fragment re-reads were
// L3-served (each XCD's L2 thrashed because batches scattered across XCDs).
// R5:
//   - XCD swizzle: 1D grids with b = blockIdx.x & 7 -> all blocks of batch b
//     on XCD b; per-XCD working set ~2.1 MB, L2-resident ACROSS kernels.
//   - k_fused1 = agg1 + dense1 + (h@W2_l)^T + h@W2_r: agg partials combined
//     into LDS acat_s tile, dense phases run from LDS; acat1 round-trip gone.
//   - kernels: k_prep (bits/xcat/xT/weights), k_fused1, k_agg2out.
// ws (~16 MB): W1cT | W2cT | deg_inv | bits | xT | xcat | hlT | hr

#define B_   8
#define N_   2048
#define INC  128
#define HID  256
#define OUTC 32

typedef __attribute__((ext_vector_type(8))) __bf16 bf16x8;
typedef __attribute__((ext_vector_type(4))) float f32x4;
typedef __attribute__((ext_vector_type(4))) unsigned int u32x4;
typedef __attribute__((ext_vector_type(2))) unsigned int u32x2;

__device__ __forceinline__ unsigned short f2bf(float f) {
  unsigned int u = __float_as_uint(f);
  u += 0x7FFFu + ((u >> 16) & 1u);  // round-to-nearest-even
  return (unsigned short)(u >> 16);
}

__device__ __forceinline__ f32x4 mfma16(bf16x8 a, bf16x8 b, f32x4 c) {
  return __builtin_amdgcn_mfma_f32_16x16x32_bf16(a, b, c, 0, 0, 0);
}

__device__ __forceinline__ bf16x8 ones_frag() {
  union { unsigned short u[8]; bf16x8 v; } o;
#pragma unroll
  for (int i = 0; i < 8; i++) o.u[i] = 0x3F80;
  return o.v;
}

__device__ __forceinline__ void lut_init(u32x2* lut, int t) {
  if (t < 16) {
    unsigned int w0 = (t & 1 ? 0x3F80u : 0u) | (t & 2 ? 0x3F800000u : 0u);
    unsigned int w1 = (t & 4 ? 0x3F80u : 0u) | (t & 8 ? 0x3F800000u : 0u);
    u32x2 e = {w0, w1};
    lut[t] = e;
  }
}

// nibble-LUT expansion: 8 mask bits -> bf16x8 (0.0/1.0)
__device__ __forceinline__ bf16x8 expand8(const u32x2* lut, unsigned int bval) {
  union { u32x2 u2[2]; bf16x8 v; } af;
  af.u2[0] = lut[bval & 15u];
  af.u2[1] = lut[bval >> 4];
  return af.v;
}

// ---------------------------------------------------------------------------
// Fused prep. Blocks (XCD-swizzled: batch = bx & 7 for per-batch sections):
//  [0,2048):    A[b][i][j] -> bits[b][j][i/32] via per-wave 64x64 ballot tiles
//  [2048,2304): x fp32 -> xT[b][d][i] bf16 AND xcat[b][i][d] bf16
//  [2304,2368): W1cT[e][k]: k<128 -> W1_l[k][e], else W1_r[k-128][e]
//  [2368,2384): W2cT[n][k]: n<32 -> W2_l[k][n], else W2_r[k][n-32]
__global__ __launch_bounds__(256, 8) void k_prep(
    const int* __restrict__ A, const float* __restrict__ x,
    const float* __restrict__ W1l, const float* __restrict__ W1r,
    const float* __restrict__ W2l, const float* __restrict__ W2r,
    unsigned int* __restrict__ bits, unsigned short* __restrict__ xT,
    unsigned short* __restrict__ xcat,
    unsigned short* __restrict__ W1cT, unsigned short* __restrict__ W2cT) {
  __shared__ unsigned short xls[128 * 72];
  const int bx = blockIdx.x, t = threadIdx.x;
  if (bx < 2048) {
    const int w = t >> 6, l = t & 63;
    const int b = bx & 7, tile4 = bx >> 3;   // XCD swizzle: batch b -> XCD b
    const int gw2 = tile4 * 4 + w;           // [0,1024)
    const int it = gw2 >> 5, jt = gw2 & 31;
    const int i0 = it * 64, j0 = jt * 64;
    const int* Ap = A + ((size_t)(b * N_) + i0) * N_ + j0 + l;
    unsigned long long col = 0;
#pragma unroll 8
    for (int r = 0; r < 64; r++) {
      int a = Ap[(size_t)r * N_];
      unsigned long long m = __ballot(a != 0);
      col |= ((m >> l) & 1ull) << r;
    }
    *reinterpret_cast<unsigned long long*>(
        bits + ((size_t)(b * N_) + j0 + l) * 64 + (i0 >> 5)) = col;
  } else if (bx < 2304) {
    const int bb = bx - 2048;
    const int b = bb & 7, it = bb >> 3;      // XCD swizzle
    const int i0 = it * 64;
    const int dq = (t & 31) * 4;
    const int irow = t >> 5;
#pragma unroll
    for (int s = 0; s < 8; s++) {
      int il = s * 8 + irow;
      int i = i0 + il;
      f32x4 v = *reinterpret_cast<const f32x4*>(x + ((size_t)(b * N_ + i)) * INC + dq);
      unsigned int p0 = f2bf(v[0]) | ((unsigned int)f2bf(v[1]) << 16);
      unsigned int p1 = f2bf(v[2]) | ((unsigned int)f2bf(v[3]) << 16);
      u32x2 pk = {p0, p1};
      *reinterpret_cast<u32x2*>(xcat + ((size_t)(b * N_ + i)) * INC + dq) = pk;
      xls[(dq + 0) * 72 + il] = f2bf(v[0]);
      xls[(dq + 1) * 72 + il] = f2bf(v[1]);
      xls[(dq + 2) * 72 + il] = f2bf(v[2]);
      xls[(dq + 3) * 72 + il] = f2bf(v[3]);
    }
    __syncthreads();
    const int d = t >> 1, half = t & 1;
    const u32x4* src = reinterpret_cast<const u32x4*>(&xls[d * 72 + half * 32]);
    u32x4* dst = reinterpret_cast<u32x4*>(xT + ((size_t)(b * INC + d)) * N_ + i0 + half * 32);
#pragma unroll
    for (int q = 0; q < 4; q++) dst[q] = src[q];
  } else if (bx < 2368) {
    int base = (bx - 2304) * 1024 + t * 4;
#pragma unroll
    for (int q = 0; q < 4; q++) {
      int id = base + q;
      int e = id >> 8, k = id & 255;
      float v = (k < 128) ? W1l[k * 256 + e] : W1r[(k - 128) * 256 + e];
      W1cT[id] = f2bf(v);
    }
  } else {
    int base = (bx - 2368) * 1024 + t * 4;
#pragma unroll
    for (int q = 0; q < 4; q++) {
      int id = base + q;
      int n = id >> 8, k = id & 255;
      float v = (n < 32) ? W2l[k * 32 + n] : W2r[k * 32 + (n - 32)];
      W2cT[id] = f2bf(v);
    }
  }
}

// ---------------------------------------------------------------------------
// Fused layer 1: agg (maskT@x, deg in-GEMM, 4-way K-split, 32j x 128d wave
// tile) -> LDS combine -> acat_s[32][264] (agg | x) -> dense1 (relu,@W1) in
// LDS -> hlT = (h@W2_l)^T bf16, hr = h@W2_r + b2 fp32.
// Grid 512 (b = bx&7 -> XCD b, j0 = (bx>>3)*32), 256 thr.
__global__ __launch_bounds__(256, 2) void k_fused1(
    const unsigned int* __restrict__ bits, const unsigned short* __restrict__ xT,
    const unsigned short* __restrict__ xcat,
    const unsigned short* __restrict__ W1cT, const unsigned short* __restrict__ W2cT,
    const float* __restrict__ b1, const float* __restrict__ b2,
    unsigned short* __restrict__ hlT, float* __restrict__ hr,
    float* __restrict__ deg_inv) {
  __shared__ u32x2 lut[16];
  __shared__ __align__(16) float pdeg[4][2][16][4];          // 2 KB
  __shared__ __align__(16) unsigned short acat_s[32 * 264];  // 16.5 KB
  union SU {
    float part[4][6][2][64][4];    // 48 KB: [src_wave][dsi(6 non-owned)][jt][l][r]
    unsigned short hs[32 * 264];   // aliased after combine reads complete
  };
  __shared__ __align__(16) SU su;

  const int t = threadIdx.x;
  const int w = t >> 6, l = t & 63, lr = l & 15, lq = l >> 4;
  lut_init(lut, t);

  const int b = blockIdx.x & 7, j0 = (blockIdx.x >> 3) * 32;

  // early x-part load (cols 128..255 of acat = x in bf16): 32 rows x 128 cols
  const int xr = t >> 3, xs = t & 7;
  const unsigned short* xp = xcat + ((size_t)(b * N_ + j0 + xr)) * INC + xs * 16;
  u32x4 xpart0 = *reinterpret_cast<const u32x4*>(xp);
  u32x4 xpart1 = *reinterpret_cast<const u32x4*>(xp + 8);

  __syncthreads();  // lut ready

  const unsigned int* bp0 = bits + ((size_t)(b * N_ + j0 + lr)) * 64 + w * 16;
  const unsigned int* bp1 = bp0 + (size_t)16 * 64;  // jt=1 -> j += 16
  const unsigned short* xb = xT + (size_t)b * INC * N_ + w * 512;

  const f32x4 zero = {0.f, 0.f, 0.f, 0.f};
  f32x4 acc[2][8];
#pragma unroll
  for (int jt = 0; jt < 2; jt++)
#pragma unroll
    for (int ds = 0; ds < 8; ds++) acc[jt][ds] = zero;
  f32x4 dacc[2] = {zero, zero};
  const bf16x8 onesf = ones_frag();

  for (int s = 0; s < 16; s++) {
    bf16x8 af0 = expand8(lut, (bp0[s] >> (lq * 8)) & 0xFFu);
    bf16x8 af1 = expand8(lut, (bp1[s] >> (lq * 8)) & 0xFFu);
    dacc[0] = mfma16(af0, onesf, dacc[0]);
    dacc[1] = mfma16(af1, onesf, dacc[1]);
#pragma unroll
    for (int ds = 0; ds < 8; ds++) {
      bf16x8 bfr = *reinterpret_cast<const bf16x8*>(
          xb + ((size_t)(ds * 16 + lr)) * N_ + s * 32 + lq * 8);
      acc[0][ds] = mfma16(af0, bfr, acc[0][ds]);
      acc[1][ds] = mfma16(af1, bfr, acc[1][ds]);
    }
  }

  // ---- step 1: dump partials (6 non-owned ds chunks), pdeg, x-part -> LDS
#pragma unroll
  for (int ds = 0; ds < 8; ds++) {
    if ((ds >> 1) != w) {
      int dsi = (ds < 2 * w) ? ds : ds - 2;
#pragma unroll
      for (int jt = 0; jt < 2; jt++)
        *reinterpret_cast<f32x4*>(&su.part[w][dsi][jt][l][0]) = acc[jt][ds];
    }
  }
  if (lr == 0) {
#pragma unroll
    for (int jt = 0; jt < 2; jt++)
      *reinterpret_cast<f32x4*>(&pdeg[w][jt][lq][0]) = dacc[jt];
  }
  *reinterpret_cast<u32x4*>(&acat_s[xr * 264 + 128 + xs * 16]) = xpart0;
  *reinterpret_cast<u32x4*>(&acat_s[xr * 264 + 128 + xs * 16 + 8]) = xpart1;
  __syncthreads();

  // ---- step 3: combine own ds chunks {2w, 2w+1}, scale, write acat_s agg part
  float dinv2[2][4];
#pragma unroll
  for (int jt = 0; jt < 2; jt++)
#pragma unroll
    for (int r = 0; r < 4; r++) {
      float deg = pdeg[0][jt][lq][r] + pdeg[1][jt][lq][r] +
                  pdeg[2][jt][lq][r] + pdeg[3][jt][lq][r];
      dinv2[jt][r] = 1.0f / fmaxf(deg, 1.0f);
    }
  if (w < 2 && lr == 0) {
#pragma unroll
    for (int r = 0; r < 4; r++)
      deg_inv[b * N_ + j0 + w * 16 + lq * 4 + r] = dinv2[w][r];
  }
#pragma unroll
  for (int dd = 0; dd < 2; dd++) {
    int ds = 2 * w + dd;
#pragma unroll
    for (int jt = 0; jt < 2; jt++) {
      f32x4 sum = acc[jt][ds];
#pragma unroll
      for (int src = 0; src < 4; src++) {
        if (src != w) {
          int dsi = (ds < 2 * src) ? ds : ds - 2;
          f32x4 p = *reinterpret_cast<f32x4*>(&su.part[src][dsi][jt][l][0]);
          sum += p;
        }
      }
#pragma unroll
      for (int r = 0; r < 4; r++)
        acat_s[(jt * 16 + lq * 4 + r) * 264 + ds * 16 + lr] =
            f2bf(sum[r] * dinv2[jt][r]);
    }
  }
  __syncthreads();

  // ---- step 5: dense1 from LDS: h = relu(acat_s @ W1cT^T + b1) -> su.hs
  f32x4 acc2[2][4];
#pragma unroll
  for (int jt = 0; jt < 2; jt++)
#pragma unroll
    for (int es = 0; es < 4; es++) acc2[jt][es] = zero;
  const int e0 = w * 64;
#pragma unroll
  for (int ks = 0; ks < 8; ks++) {
    bf16x8 af0 = *reinterpret_cast<const bf16x8*>(&acat_s[lr * 264 + ks * 32 + lq * 8]);
    bf16x8 af1 = *reinterpret_cast<const bf16x8*>(&acat_s[(16 + lr) * 264 + ks * 32 + lq * 8]);
#pragma unroll
    for (int es = 0; es < 4; es++) {
      bf16x8 bfr = *reinterpret_cast<const bf16x8*>(
          W1cT + ((size_t)(e0 + es * 16 + lr)) * HID + ks * 32 + lq * 8);
      acc2[0][es] = mfma16(af0, bfr, acc2[0][es]);
      acc2[1][es] = mfma16(af1, bfr, acc2[1][es]);
    }
  }
  __syncthreads();  // all part reads done; su.hs may now be written
#pragma unroll
  for (int jt = 0; jt < 2; jt++)
#pragma unroll
    for (int es = 0; es < 4; es++) {
      int e = e0 + es * 16 + lr;
      float bias = b1[e];
#pragma unroll
      for (int r = 0; r < 4; r++)
        su.hs[(jt * 16 + lq * 4 + r) * 264 + e] =
            f2bf(fmaxf(acc2[jt][es][r] + bias, 0.0f));
    }
  __syncthreads();

  // ---- step 7: hlT = (h@W2_l)^T bf16 (waves 0,1); hr = h@W2_r + b2 (waves 2,3)
  const int jt = w & 1, nh = w >> 1;
  f32x4 a2[2] = {zero, zero};
#pragma unroll
  for (int ks = 0; ks < 8; ks++) {
    bf16x8 af = *reinterpret_cast<const bf16x8*>(
        &su.hs[(jt * 16 + lr) * 264 + ks * 32 + lq * 8]);
#pragma unroll
    for (int ns = 0; ns < 2; ns++) {
      bf16x8 bfr = *reinterpret_cast<const bf16x8*>(
          W2cT + ((size_t)(nh * 32 + ns * 16 + lr)) * HID + ks * 32 + lq * 8);
      a2[ns] = mfma16(af, bfr, a2[ns]);
    }
  }
  if (nh == 0) {
#pragma unroll
    for (int ns = 0; ns < 2; ns++) {
      int c = ns * 16 + lr;
      unsigned int p0 = f2bf(a2[ns][0]) | ((unsigned int)f2bf(a2[ns][1]) << 16);
      unsigned int p1 = f2bf(a2[ns][2]) | ((unsigned int)f2bf(a2[ns][3]) << 16);
      u32x2 pk = {p0, p1};
      *reinterpret_cast<u32x2*>(
          hlT + ((size_t)(b * 32 + c)) * N_ + j0 + jt * 16 + lq * 4) = pk;
    }
  } else {
#pragma unroll
    for (int ns = 0; ns < 2; ns++) {
      int c = ns * 16 + lr;
      float bias = b2[c];
#pragma unroll
      for (int r = 0; r < 4; r++)
        hr[((size_t)(b * N_ + j0 + jt * 16 + lq * 4 + r)) * OUTC + c] = a2[ns][r] + bias;
    }
  }
}

// ---------------------------------------------------------------------------
// Fused layer-2 agg + epilogue + log_softmax. Wave tile 32 j x 32 c, 4-way
// K-split, 16 KB LDS combine; waves 0,1 do the epilogue (jt = w).
// Grid 512 (b = bx&7 -> XCD b, j0 = (bx>>3)*32), 256 thr.
__global__ __launch_bounds__(256, 2) void k_agg2out(
    const unsigned int* __restrict__ bits, const unsigned short* __restrict__ hlT,
    const float* __restrict__ deg_inv, const float* __restrict__ hr,
    float* __restrict__ out) {
  __shared__ u32x2 lut[16];
  __shared__ __align__(16) float part[4][2][2][64][4];  // 16 KB
  const int t = threadIdx.x;
  const int w = t >> 6, l = t & 63, lr = l & 15, lq = l >> 4;
  lut_init(lut, t);
  __syncthreads();
  const int b = blockIdx.x & 7, j0 = (blockIdx.x >> 3) * 32;
  const unsigned int* bp0 = bits + ((size_t)(b * N_ + j0 + lr)) * 64 + w * 16;
  const unsigned int* bp1 = bp0 + (size_t)16 * 64;
  const unsigned short* hb = hlT + (size_t)b * 32 * N_ + w * 512;

  const f32x4 zero = {0.f, 0.f, 0.f, 0.f};
  f32x4 acc[2][2] = {{zero, zero}, {zero, zero}};

  for (int s = 0; s < 16; s++) {
    bf16x8 af0 = expand8(lut, (bp0[s] >> (lq * 8)) & 0xFFu);
    bf16x8 af1 = expand8(lut, (bp1[s] >> (lq * 8)) & 0xFFu);
#pragma unroll
    for (int cs = 0; cs < 2; cs++) {
      bf16x8 bfr = *reinterpret_cast<const bf16x8*>(
          hb + ((size_t)(cs * 16 + lr)) * N_ + s * 32 + lq * 8);
      acc[0][cs] = mfma16(af0, bfr, acc[0][cs]);
      acc[1][cs] = mfma16(af1, bfr, acc[1][cs]);
    }
  }
#pragma unroll
  for (int jt = 0; jt < 2; jt++)
#pragma unroll
    for (int cs = 0; cs < 2; cs++)
      *reinterpret_cast<f32x4*>(&part[w][jt][cs][l][0]) = acc[jt][cs];
  __syncthreads();
  if (w >= 2) return;

  const int jt = w;
  const size_t SZ = (size_t)B_ * N_ * OUTC;
#pragma unroll
  for (int r = 0; r < 4; r++) {
    int j = j0 + jt * 16 + lq * 4 + r;
    float dv = deg_inv[b * N_ + j];
    size_t base = ((size_t)(b * N_ + j)) * OUTC;
    float v0 = (part[0][jt][0][l][r] + part[1][jt][0][l][r] +
                part[2][jt][0][l][r] + part[3][jt][0][l][r]) * dv + hr[base + lr];
    float v1 = (part[0][jt][1][l][r] + part[1][jt][1][l][r] +
                part[2][jt][1][l][r] + part[3][jt][1][l][r]) * dv + hr[base + 16 + lr];
    float m = fmaxf(v0, v1);
#pragma unroll
    for (int d = 1; d < 16; d <<= 1) m = fmaxf(m, __shfl_xor(m, d, 64));
    float s = __expf(v0 - m) + __expf(v1 - m);
#pragma unroll
    for (int d = 1; d < 16; d <<= 1) s += __shfl_xor(s, d, 64);
    float ls = m + __logf(s);
    out[base + lr] = v0 - ls;
    out[base + 16 + lr] = v1 - ls;
    out[SZ + base + lr] = v0;
    out[SZ + base + 16 + lr] = v1;
  }
}

// ---------------------------------------------------------------------------
extern "C" void kernel_launch(void* const* d_in, const int* in_sizes, int n_in,
                              void* d_out, int out_size, void* d_ws, size_t ws_size,
                              hipStream_t stream) {
  (void)in_sizes; (void)n_in; (void)out_size; (void)ws_size;
  const float* x   = (const float*)d_in[0];
  const int*   A   = (const int*)d_in[1];
  const float* W1l = (const float*)d_in[2];
  const float* W1r = (const float*)d_in[3];
  const float* b1  = (const float*)d_in[4];
  const float* W2l = (const float*)d_in[5];
  const float* W2r = (const float*)d_in[6];
  const float* b2  = (const float*)d_in[7];
  float* out = (float*)d_out;

  char* ws = (char*)d_ws;
  unsigned short* W1cT    = (unsigned short*)(ws + 0);         // 131072
  unsigned short* W2cT    = (unsigned short*)(ws + 131072);    // -> 163840
  float*          deg_inv = (float*)(ws + 163840);             // -> 229376
  unsigned int*   bits    = (unsigned int*)(ws + 229376);      // 4 MB -> 4423680
  unsigned short* xT      = (unsigned short*)(ws + 4423680);   // 4 MB -> 8617984
  unsigned short* xcat    = (unsigned short*)(ws + 8617984);   // 4 MB -> 12812288
  unsigned short* hlT     = (unsigned short*)(ws + 12812288);  // 1 MB -> 13860864
  float*          hr      = (float*)(ws + 13860864);           // 2 MB -> 15958016

  k_prep   <<<dim3(2384), dim3(256), 0, stream>>>(A, x, W1l, W1r, W2l, W2r,
                                                  bits, xT, xcat, W1cT, W2cT);
  k_fused1 <<<dim3(512),  dim3(256), 0, stream>>>(bits, xT, xcat, W1cT, W2cT,
                                                  b1, b2, hlT, hr, deg_inv);
  k_agg2out<<<dim3(512),  dim3(256), 0, stream>>>(bits, hlT, deg_inv, hr, out);
}